// Round 5
// baseline (123.846 us; speedup 1.0000x reference)
//
#include <hip/hip_runtime.h>

// EdgeConv forward via MFMA (bf16 inputs, fp32 accumulate). Round 5.
//
// DIFFERENTIAL-MEASUREMENT ROUND: launches prep + edgeconv_mfma (R4, known
// good) + edgeconv_v5 (reordered issue). Both edge kernels write identical
// values to out (idempotent), v5 last so correctness validates v5.
// dur_R5 - dur_R4 ~= time(v5) + launch gap -> decides whether the edge
// kernel is ~10us (harness floor dominates) or ~40us (gather-bound).
//
// Math: out[i] = max_j relu(W @ concat(x_i, x_j - x_i) + b), DEG=16 contiguous.
// Split W=[W1|W2]: msg = base + x_j.W2^T, base = b + x_i.(W1-W2)^T.
// Fragment layouts (m89/m91-verified):
//   A[m=lane&15][k=(lane>>4)*8+j] -> bytes at row*C + ks*32 + quad*8
//   B[k=(lane>>4)*8+j][n=lane&15],  D: col=lane&15, row=(lane>>4)*4+reg

#define DEG 16
#define C 64
#define NPW 4    // nodes per wave
#define WPB 4    // waves per block

typedef __attribute__((ext_vector_type(8))) short s16x8;  // 8 bf16 = 4 VGPRs
typedef __attribute__((ext_vector_type(4))) float f32x4;  // MFMA C/D

__device__ __forceinline__ unsigned short f2bf(float f) {
    union { float f; unsigned u; } v; v.f = f;
    unsigned u = v.u + 0x7FFFu + ((v.u >> 16) & 1u);  // round-nearest-even
    return (unsigned short)(u >> 16);
}

// ws layout (ushorts): [ x_bf16 : N*C ][ wfrag table : 16*64*8 ]
// wfrag slot f = which*8 + nt*2 + ks (0=bd=(W1-W2)^T, 1=b2=W2^T); lane frag at (f*64+l)*8.

__global__ __launch_bounds__(256) void prep(const float* __restrict__ x,
                                            const float* __restrict__ W,
                                            unsigned short* __restrict__ ws_u,
                                            int n4) {
    int i = blockIdx.x * blockDim.x + threadIdx.x;
    if (i < n4) {
        f32x4 v = ((const f32x4*)x)[i];
        ushort4 o;
        o.x = f2bf(v[0]); o.y = f2bf(v[1]); o.z = f2bf(v[2]); o.w = f2bf(v[3]);
        ((ushort4*)ws_u)[i] = o;
    }
    if (blockIdx.x == 0 && threadIdx.x < 64) {
        const int lane = threadIdx.x, col = lane & 15, quad = lane >> 4;
        unsigned short* wf = ws_u + (size_t)n4 * 4;
        #pragma unroll
        for (int nt = 0; nt < 4; ++nt) {
            const float* wrow = W + (nt * 16 + col) * (2 * C);
            #pragma unroll
            for (int ks = 0; ks < 2; ++ks) {
                const int k0 = ks * 32 + quad * 8;
                f32x4 w1a = *(const f32x4*)(wrow + k0);
                f32x4 w1b = *(const f32x4*)(wrow + k0 + 4);
                f32x4 w2a = *(const f32x4*)(wrow + C + k0);
                f32x4 w2b = *(const f32x4*)(wrow + C + k0 + 4);
                s16x8 t2, td;
                #pragma unroll
                for (int j = 0; j < 4; ++j) {
                    t2[j]     = (short)f2bf(w2a[j]);
                    t2[j + 4] = (short)f2bf(w2b[j]);
                    td[j]     = (short)f2bf(w1a[j] - w2a[j]);
                    td[j + 4] = (short)f2bf(w1b[j] - w2b[j]);
                }
                *(s16x8*)(wf + (((0 * 8) + nt * 2 + ks) * 64 + lane) * 8) = td;
                *(s16x8*)(wf + (((1 * 8) + nt * 2 + ks) * 64 + lane) * 8) = t2;
            }
        }
    }
}

// ---------------- R4 kernel (A), unchanged ----------------
__global__ __launch_bounds__(256, 4) void edgeconv_mfma(
    const unsigned short* __restrict__ xb, const int* __restrict__ src,
    const float* __restrict__ bias, float* __restrict__ out,
    int n_groups, int n_nodes)
{
    const int lane = threadIdx.x & 63;
    const int wave = threadIdx.x >> 6;
    const int col  = lane & 15;
    const int quad = lane >> 4;
    int group = blockIdx.x * WPB + wave;
    if (group >= n_groups) group = n_groups - 1;
    const int node0 = group * NPW;

    int idx[NPW];
    #pragma unroll
    for (int n = 0; n < NPW; ++n)
        idx[n] = src[node0 * DEG + n * DEG + col];

    const unsigned short* wf = xb + (size_t)n_nodes * C;
    s16x8 bd[4][2], b2[4][2];
    #pragma unroll
    for (int nt = 0; nt < 4; ++nt)
        #pragma unroll
        for (int ks = 0; ks < 2; ++ks) {
            bd[nt][ks] = *(const s16x8*)(wf + ((nt * 2 + ks) * 64 + lane) * 8);
            b2[nt][ks] = *(const s16x8*)(wf + ((8 + nt * 2 + ks) * 64 + lane) * 8);
        }

    const int xirow = node0 + (col & 3);
    s16x8 xi0 = *(const s16x8*)(xb + xirow * C + quad * 8);
    s16x8 xi1 = *(const s16x8*)(xb + xirow * C + 32 + quad * 8);
    f32x4 baseD[4];
    #pragma unroll
    for (int nt = 0; nt < 4; ++nt) {
        float bv = bias[nt * 16 + col];
        baseD[nt] = (f32x4){bv, bv, bv, bv};
    }
    #pragma unroll
    for (int nt = 0; nt < 4; ++nt) {
        baseD[nt] = __builtin_amdgcn_mfma_f32_16x16x32_bf16(xi0, bd[nt][0], baseD[nt], 0, 0, 0);
        baseD[nt] = __builtin_amdgcn_mfma_f32_16x16x32_bf16(xi1, bd[nt][1], baseD[nt], 0, 0, 0);
    }

    s16x8 xa[NPW][2];
    #pragma unroll
    for (int n = 0; n < NPW; ++n) {
        xa[n][0] = *(const s16x8*)(xb + idx[n] * C + quad * 8);
        xa[n][1] = *(const s16x8*)(xb + idx[n] * C + 32 + quad * 8);
    }

    #pragma unroll
    for (int n = 0; n < NPW; ++n) {
        f32x4 acc[4];
        #pragma unroll
        for (int nt = 0; nt < 4; ++nt) {
            float bb = __shfl(baseD[nt][n], col);
            acc[nt] = (f32x4){bb, bb, bb, bb};
        }
        #pragma unroll
        for (int nt = 0; nt < 4; ++nt) {
            acc[nt] = __builtin_amdgcn_mfma_f32_16x16x32_bf16(xa[n][0], b2[nt][0], acc[nt], 0, 0, 0);
            acc[nt] = __builtin_amdgcn_mfma_f32_16x16x32_bf16(xa[n][1], b2[nt][1], acc[nt], 0, 0, 0);
        }
        float m[4];
        #pragma unroll
        for (int nt = 0; nt < 4; ++nt) {
            float t = fmaxf(fmaxf(acc[nt][0], acc[nt][1]),
                            fmaxf(acc[nt][2], acc[nt][3]));
            t = fmaxf(t, __shfl_xor(t, 16));
            t = fmaxf(t, __shfl_xor(t, 32));
            m[nt] = t;
        }
        float r = quad == 0 ? m[0] : quad == 1 ? m[1] : quad == 2 ? m[2] : m[3];
        out[(node0 + n) * C + lane] = fmaxf(r, 0.0f);
    }
}

// ---------------- v5 (B): gather chain issued FIRST ----------------
__global__ __launch_bounds__(256, 4) void edgeconv_v5(
    const unsigned short* __restrict__ xb, const int* __restrict__ src,
    const float* __restrict__ bias, float* __restrict__ out,
    int n_groups, int n_nodes)
{
    const int lane = threadIdx.x & 63;
    const int wave = threadIdx.x >> 6;
    const int col  = lane & 15;
    const int quad = lane >> 4;
    int group = blockIdx.x * WPB + wave;
    if (group >= n_groups) group = n_groups - 1;
    const int node0 = group * NPW;

    // 1. longest dependent chain first: idx -> all 8 gathers
    int idx[NPW];
    #pragma unroll
    for (int n = 0; n < NPW; ++n)
        idx[n] = src[node0 * DEG + n * DEG + col];
    s16x8 xa[NPW][2];
    #pragma unroll
    for (int n = 0; n < NPW; ++n) {
        xa[n][0] = *(const s16x8*)(xb + idx[n] * C + quad * 8);
        xa[n][1] = *(const s16x8*)(xb + idx[n] * C + 32 + quad * 8);
    }

    // 2. W-table, xi, bias (independent loads; execute under gather latency)
    const unsigned short* wf = xb + (size_t)n_nodes * C;
    s16x8 bd[4][2], b2[4][2];
    #pragma unroll
    for (int nt = 0; nt < 4; ++nt)
        #pragma unroll
        for (int ks = 0; ks < 2; ++ks) {
            bd[nt][ks] = *(const s16x8*)(wf + ((nt * 2 + ks) * 64 + lane) * 8);
            b2[nt][ks] = *(const s16x8*)(wf + ((8 + nt * 2 + ks) * 64 + lane) * 8);
        }
    const int xirow = node0 + (col & 3);
    s16x8 xi0 = *(const s16x8*)(xb + xirow * C + quad * 8);
    s16x8 xi1 = *(const s16x8*)(xb + xirow * C + 32 + quad * 8);

    // 3. stage 1 (overlaps the still-in-flight gathers)
    f32x4 baseD[4];
    #pragma unroll
    for (int nt = 0; nt < 4; ++nt) {
        float bv = bias[nt * 16 + col];
        baseD[nt] = (f32x4){bv, bv, bv, bv};
    }
    #pragma unroll
    for (int nt = 0; nt < 4; ++nt) {
        baseD[nt] = __builtin_amdgcn_mfma_f32_16x16x32_bf16(xi0, bd[nt][0], baseD[nt], 0, 0, 0);
        baseD[nt] = __builtin_amdgcn_mfma_f32_16x16x32_bf16(xi1, bd[nt][1], baseD[nt], 0, 0, 0);
    }

    // 4. stage 2 + epilogue
    #pragma unroll
    for (int n = 0; n < NPW; ++n) {
        f32x4 acc[4];
        #pragma unroll
        for (int nt = 0; nt < 4; ++nt) {
            float bb = __shfl(baseD[nt][n], col);
            acc[nt] = (f32x4){bb, bb, bb, bb};
        }
        #pragma unroll
        for (int nt = 0; nt < 4; ++nt) {
            acc[nt] = __builtin_amdgcn_mfma_f32_16x16x32_bf16(xa[n][0], b2[nt][0], acc[nt], 0, 0, 0);
            acc[nt] = __builtin_amdgcn_mfma_f32_16x16x32_bf16(xa[n][1], b2[nt][1], acc[nt], 0, 0, 0);
        }
        float m[4];
        #pragma unroll
        for (int nt = 0; nt < 4; ++nt) {
            float t = fmaxf(fmaxf(acc[nt][0], acc[nt][1]),
                            fmaxf(acc[nt][2], acc[nt][3]));
            t = fmaxf(t, __shfl_xor(t, 16));
            t = fmaxf(t, __shfl_xor(t, 32));
            m[nt] = t;
        }
        float r = quad == 0 ? m[0] : quad == 1 ? m[1] : quad == 2 ? m[2] : m[3];
        out[(node0 + n) * C + lane] = fmaxf(r, 0.0f);
    }
}

// Fallback (no ws): R3-proven kernel.
__global__ __launch_bounds__(256, 2) void edgeconv_fallback(
    const float* __restrict__ x, const int* __restrict__ src,
    const float* __restrict__ W, const float* __restrict__ bias,
    float* __restrict__ out, int n_groups)
{
    const int lane = threadIdx.x & 63, wave = threadIdx.x >> 6;
    const int col = lane & 15, quad = lane >> 4;
    int group = blockIdx.x * WPB + wave;
    if (group >= n_groups) group = n_groups - 1;

    auto frag = [&](int row, int koff) {
        const float* p = x + row * C + koff;
        f32x4 a = *(const f32x4*)p, b = *(const f32x4*)(p + 4);
        s16x8 r;
        #pragma unroll
        for (int j = 0; j < 4; ++j) {
            r[j] = (short)f2bf(a[j]); r[j + 4] = (short)f2bf(b[j]);
        }
        return r;
    };

    s16x8 b2[4][2];
    f32x4 baseD[4];
    {
        s16x8 bd[4][2];
        #pragma unroll
        for (int nt = 0; nt < 4; ++nt) {
            const float* wrow = W + (nt * 16 + col) * (2 * C);
            #pragma unroll
            for (int ks = 0; ks < 2; ++ks) {
                const int k0 = ks * 32 + quad * 8;
                f32x4 w1a = *(const f32x4*)(wrow + k0);
                f32x4 w1b = *(const f32x4*)(wrow + k0 + 4);
                f32x4 w2a = *(const f32x4*)(wrow + C + k0);
                f32x4 w2b = *(const f32x4*)(wrow + C + k0 + 4);
                s16x8 t2, td;
                #pragma unroll
                for (int j = 0; j < 4; ++j) {
                    t2[j] = (short)f2bf(w2a[j]); t2[j + 4] = (short)f2bf(w2b[j]);
                    td[j] = (short)f2bf(w1a[j] - w2a[j]);
                    td[j + 4] = (short)f2bf(w1b[j] - w2b[j]);
                }
                b2[nt][ks] = t2; bd[nt][ks] = td;
            }
        }
        #pragma unroll
        for (int nt = 0; nt < 4; ++nt) {
            float bv = bias[nt * 16 + col];
            baseD[nt] = (f32x4){bv, bv, bv, bv};
        }
        const int nrow = group * 16 + col;
        s16x8 xi0 = frag(nrow, quad * 8), xi1 = frag(nrow, 32 + quad * 8);
        #pragma unroll
        for (int nt = 0; nt < 4; ++nt) {
            baseD[nt] = __builtin_amdgcn_mfma_f32_16x16x32_bf16(xi0, bd[nt][0], baseD[nt], 0, 0, 0);
            baseD[nt] = __builtin_amdgcn_mfma_f32_16x16x32_bf16(xi1, bd[nt][1], baseD[nt], 0, 0, 0);
        }
    }
    int idx[16];
    #pragma unroll
    for (int n = 0; n < 16; ++n) idx[n] = src[group * 256 + n * DEG + col];
    s16x8 xa[3][2];
    #pragma unroll
    for (int p = 0; p < 2; ++p) {
        xa[p][0] = frag(idx[p], quad * 8); xa[p][1] = frag(idx[p], 32 + quad * 8);
    }
    #pragma unroll
    for (int n = 0; n < 16; ++n) {
        if (n + 2 < 16) {
            xa[(n + 2) % 3][0] = frag(idx[n + 2], quad * 8);
            xa[(n + 2) % 3][1] = frag(idx[n + 2], 32 + quad * 8);
        }
        const int slane = ((n >> 2) << 4) | col;
        f32x4 acc[4];
        #pragma unroll
        for (int nt = 0; nt < 4; ++nt) {
            float bb = __shfl(baseD[nt][n & 3], slane);
            acc[nt] = (f32x4){bb, bb, bb, bb};
        }
        #pragma unroll
        for (int nt = 0; nt < 4; ++nt) {
            acc[nt] = __builtin_amdgcn_mfma_f32_16x16x32_bf16(xa[n % 3][0], b2[nt][0], acc[nt], 0, 0, 0);
            acc[nt] = __builtin_amdgcn_mfma_f32_16x16x32_bf16(xa[n % 3][1], b2[nt][1], acc[nt], 0, 0, 0);
        }
        float m[4];
        #pragma unroll
        for (int nt = 0; nt < 4; ++nt) {
            float t = fmaxf(fmaxf(acc[nt][0], acc[nt][1]),
                            fmaxf(acc[nt][2], acc[nt][3]));
            t = fmaxf(t, __shfl_xor(t, 16));
            t = fmaxf(t, __shfl_xor(t, 32));
            m[nt] = t;
        }
        float r = quad == 0 ? m[0] : quad == 1 ? m[1] : quad == 2 ? m[2] : m[3];
        out[(group * 16 + n) * C + lane] = fmaxf(r, 0.0f);
    }
}

extern "C" void kernel_launch(void* const* d_in, const int* in_sizes, int n_in,
                              void* d_out, int out_size, void* d_ws, size_t ws_size,
                              hipStream_t stream) {
    const float* x    = (const float*)d_in[0];
    const int*   src  = (const int*)  d_in[1];
    const float* W    = (const float*)d_in[3];
    const float* b    = (const float*)d_in[4];
    float*       out  = (float*)d_out;

    const int n_nodes = in_sizes[0] / C;
    const size_t need = ((size_t)n_nodes * C + 16 * 64 * 8) * sizeof(unsigned short);

    if (ws_size >= need) {
        unsigned short* ws_u = (unsigned short*)d_ws;
        const int n4 = n_nodes * C / 4;
        const int n_groups = (n_nodes + NPW - 1) / NPW;
        const int grid = (n_groups + WPB - 1) / WPB;
        prep<<<(n4 + 255) / 256, 256, 0, stream>>>(x, W, ws_u, n4);
        // A: known-good R4 kernel. B: v5. Same outputs; B last -> correctness
        // validates B; dur_R5 - dur_R4 ~= time(B) + launch gap.
        edgeconv_mfma<<<grid, 256, 0, stream>>>(ws_u, src, b, out, n_groups, n_nodes);
        edgeconv_v5 <<<grid, 256, 0, stream>>>(ws_u, src, b, out, n_groups, n_nodes);
    } else {
        const int n_groups = (n_nodes + 15) / 16;
        edgeconv_fallback<<<(n_groups + WPB - 1) / WPB, 256, 0, stream>>>(
            x, src, W, b, out, n_groups);
    }
}

// Round 6
// 97.824 us; speedup vs baseline: 1.2660x; 1.2660x over previous
//
#include <hip/hip_runtime.h>

// EdgeConv forward via MFMA (bf16 inputs, fp32 accumulate). Round 6.
//
// out[i] = max_j relu(W @ concat(x_i, x_j - x_i) + b), DEG=16 contiguous/node.
// Split W=[W1|W2]: msg = base + x_j.W2^T, base = b + x_i.(W1-W2)^T.
//
// Timing model (R5 differential): dur ~= 75us harness floor (ws-poison fill
// 47us + out poison + restores + graph gaps) + prep ~5us + edge ~20us.
// Edge kernel cost ~= random-line gather service (102 MB: 800k edges x 128B
// bf16 row, each row consumed exactly once per edge) + per-wave overheads.
//
// R6: single edge launch (v5 differential copy dropped), NPW 4->8 @
// launch_bounds(256,3): halves per-node idx/W-table/xi/stage-1 overhead,
// 16 outstanding gather dwordx4 per wave, fewer latency generations.
//
// Fragment layouts (m89/m91-verified):
//   A[m=lane&15][k=(lane>>4)*8+j] -> bytes at row*C + ks*32 + quad*8
//   B[k=(lane>>4)*8+j][n=lane&15],  D: col=lane&15, row=(lane>>4)*4+reg

#define DEG 16
#define C 64
#define NPW 8    // nodes per wave
#define WPB 4    // waves per block

typedef __attribute__((ext_vector_type(8))) short s16x8;  // 8 bf16 = 4 VGPRs
typedef __attribute__((ext_vector_type(4))) float f32x4;  // MFMA C/D

__device__ __forceinline__ unsigned short f2bf(float f) {
    union { float f; unsigned u; } v; v.f = f;
    unsigned u = v.u + 0x7FFFu + ((v.u >> 16) & 1u);  // round-nearest-even
    return (unsigned short)(u >> 16);
}

// ws layout (ushorts): [ x_bf16 : N*C ][ wfrag table : 16*64*8 ]
// wfrag slot f = which*8 + nt*2 + ks (0=bd=(W1-W2)^T, 1=b2=W2^T); lane frag at (f*64+l)*8.

__global__ __launch_bounds__(256) void prep(const float* __restrict__ x,
                                            const float* __restrict__ W,
                                            unsigned short* __restrict__ ws_u,
                                            int n4) {
    int i = blockIdx.x * blockDim.x + threadIdx.x;
    if (i < n4) {
        f32x4 v = ((const f32x4*)x)[i];
        ushort4 o;
        o.x = f2bf(v[0]); o.y = f2bf(v[1]); o.z = f2bf(v[2]); o.w = f2bf(v[3]);
        ((ushort4*)ws_u)[i] = o;
    }
    if (blockIdx.x == 0 && threadIdx.x < 64) {
        const int lane = threadIdx.x, col = lane & 15, quad = lane >> 4;
        unsigned short* wf = ws_u + (size_t)n4 * 4;
        #pragma unroll
        for (int nt = 0; nt < 4; ++nt) {
            const float* wrow = W + (nt * 16 + col) * (2 * C);
            #pragma unroll
            for (int ks = 0; ks < 2; ++ks) {
                const int k0 = ks * 32 + quad * 8;
                f32x4 w1a = *(const f32x4*)(wrow + k0);
                f32x4 w1b = *(const f32x4*)(wrow + k0 + 4);
                f32x4 w2a = *(const f32x4*)(wrow + C + k0);
                f32x4 w2b = *(const f32x4*)(wrow + C + k0 + 4);
                s16x8 t2, td;
                #pragma unroll
                for (int j = 0; j < 4; ++j) {
                    t2[j]     = (short)f2bf(w2a[j]);
                    t2[j + 4] = (short)f2bf(w2b[j]);
                    td[j]     = (short)f2bf(w1a[j] - w2a[j]);
                    td[j + 4] = (short)f2bf(w1b[j] - w2b[j]);
                }
                *(s16x8*)(wf + (((0 * 8) + nt * 2 + ks) * 64 + lane) * 8) = td;
                *(s16x8*)(wf + (((1 * 8) + nt * 2 + ks) * 64 + lane) * 8) = t2;
            }
        }
    }
}

__global__ __launch_bounds__(256, 3) void edgeconv_mfma(
    const unsigned short* __restrict__ xb,    // [N,64] bf16 (in ws)
    const int* __restrict__ src,              // [E] edge sources
    const float* __restrict__ bias,           // [64]
    float* __restrict__ out,                  // [N,64]
    int n_groups, int n_nodes)
{
    const int lane = threadIdx.x & 63;
    const int wave = threadIdx.x >> 6;
    const int col  = lane & 15;
    const int quad = lane >> 4;
    int group = blockIdx.x * WPB + wave;
    if (group >= n_groups) group = n_groups - 1;  // dup work, identical writes
    const int node0 = group * NPW;

    // ---- 1. edge indices (head of the longest dependent chain) ----
    int idx[NPW];
    #pragma unroll
    for (int n = 0; n < NPW; ++n)
        idx[n] = src[node0 * DEG + n * DEG + col];  // lane's A-row = edge col

    // ---- 2. W fragments from the prebuilt table (coalesced, L2-hot) ----
    const unsigned short* wf = xb + (size_t)n_nodes * C;
    s16x8 bd[4][2], b2[4][2];
    #pragma unroll
    for (int nt = 0; nt < 4; ++nt)
        #pragma unroll
        for (int ks = 0; ks < 2; ++ks) {
            bd[nt][ks] = *(const s16x8*)(wf + ((nt * 2 + ks) * 64 + lane) * 8);
            b2[nt][ks] = *(const s16x8*)(wf + ((8 + nt * 2 + ks) * 64 + lane) * 8);
        }

    // ---- 3. stage 1: base = bias + XI @ (W1-W2)^T ----
    // A rows 0..7 = the wave's 8 nodes (rows 8..15 dup via col&7: harmless).
    const int xirow = node0 + (col & 7);
    s16x8 xi0 = *(const s16x8*)(xb + xirow * C + quad * 8);
    s16x8 xi1 = *(const s16x8*)(xb + xirow * C + 32 + quad * 8);
    f32x4 baseD[4];
    #pragma unroll
    for (int nt = 0; nt < 4; ++nt) {
        float bv = bias[nt * 16 + col];
        baseD[nt] = (f32x4){bv, bv, bv, bv};
    }
    #pragma unroll
    for (int nt = 0; nt < 4; ++nt) {
        baseD[nt] = __builtin_amdgcn_mfma_f32_16x16x32_bf16(xi0, bd[nt][0], baseD[nt], 0, 0, 0);
        baseD[nt] = __builtin_amdgcn_mfma_f32_16x16x32_bf16(xi1, bd[nt][1], baseD[nt], 0, 0, 0);
    }
    // base[node n][nt*16+c]: lane ((n>>2)<<4)|c, reg n&3.

    // ---- 4. issue ALL gathers (16 outstanding dwordx4 per lane) ----
    s16x8 xa[NPW][2];
    #pragma unroll
    for (int n = 0; n < NPW; ++n) {
        xa[n][0] = *(const s16x8*)(xb + idx[n] * C + quad * 8);
        xa[n][1] = *(const s16x8*)(xb + idx[n] * C + 32 + quad * 8);
    }

    // ---- 5. per-node: MSG = base + XJ @ W2^T, column-max, relu, store ----
    #pragma unroll
    for (int n = 0; n < NPW; ++n) {
        const int slane = ((n >> 2) << 4) | col;
        f32x4 acc[4];
        #pragma unroll
        for (int nt = 0; nt < 4; ++nt) {
            float bb = __shfl(baseD[nt][n & 3], slane);  // base[n][nt*16+col]
            acc[nt] = (f32x4){bb, bb, bb, bb};
        }
        #pragma unroll
        for (int nt = 0; nt < 4; ++nt) {
            acc[nt] = __builtin_amdgcn_mfma_f32_16x16x32_bf16(xa[n][0], b2[nt][0], acc[nt], 0, 0, 0);
            acc[nt] = __builtin_amdgcn_mfma_f32_16x16x32_bf16(xa[n][1], b2[nt][1], acc[nt], 0, 0, 0);
        }
        // max over edges (rows): 4 regs in-lane, then cross-quad shfl_xor.
        float m[4];
        #pragma unroll
        for (int nt = 0; nt < 4; ++nt) {
            float t = fmaxf(fmaxf(acc[nt][0], acc[nt][1]),
                            fmaxf(acc[nt][2], acc[nt][3]));
            t = fmaxf(t, __shfl_xor(t, 16));
            t = fmaxf(t, __shfl_xor(t, 32));
            m[nt] = t;
        }
        float r = quad == 0 ? m[0] : quad == 1 ? m[1] : quad == 2 ? m[2] : m[3];
        r = fmaxf(r, 0.0f);  // relu (monotone: fold after max)
        out[(node0 + n) * C + lane] = r;  // coalesced 256B/node
    }
}

// Fallback (no ws): R3-proven kernel, NPW=16, in-wave W build, fp32 gather.
__global__ __launch_bounds__(256, 2) void edgeconv_fallback(
    const float* __restrict__ x, const int* __restrict__ src,
    const float* __restrict__ W, const float* __restrict__ bias,
    float* __restrict__ out, int n_groups)
{
    const int lane = threadIdx.x & 63, wave = threadIdx.x >> 6;
    const int col = lane & 15, quad = lane >> 4;
    int group = blockIdx.x * WPB + wave;
    if (group >= n_groups) group = n_groups - 1;

    auto frag = [&](int row, int koff) {
        const float* p = x + row * C + koff;
        f32x4 a = *(const f32x4*)p, b = *(const f32x4*)(p + 4);
        s16x8 r;
        #pragma unroll
        for (int j = 0; j < 4; ++j) {
            r[j] = (short)f2bf(a[j]); r[j + 4] = (short)f2bf(b[j]);
        }
        return r;
    };

    s16x8 b2[4][2];
    f32x4 baseD[4];
    {
        s16x8 bd[4][2];
        #pragma unroll
        for (int nt = 0; nt < 4; ++nt) {
            const float* wrow = W + (nt * 16 + col) * (2 * C);
            #pragma unroll
            for (int ks = 0; ks < 2; ++ks) {
                const int k0 = ks * 32 + quad * 8;
                f32x4 w1a = *(const f32x4*)(wrow + k0);
                f32x4 w1b = *(const f32x4*)(wrow + k0 + 4);
                f32x4 w2a = *(const f32x4*)(wrow + C + k0);
                f32x4 w2b = *(const f32x4*)(wrow + C + k0 + 4);
                s16x8 t2, td;
                #pragma unroll
                for (int j = 0; j < 4; ++j) {
                    t2[j] = (short)f2bf(w2a[j]); t2[j + 4] = (short)f2bf(w2b[j]);
                    td[j] = (short)f2bf(w1a[j] - w2a[j]);
                    td[j + 4] = (short)f2bf(w1b[j] - w2b[j]);
                }
                b2[nt][ks] = t2; bd[nt][ks] = td;
            }
        }
        #pragma unroll
        for (int nt = 0; nt < 4; ++nt) {
            float bv = bias[nt * 16 + col];
            baseD[nt] = (f32x4){bv, bv, bv, bv};
        }
        const int nrow = group * 16 + col;
        s16x8 xi0 = frag(nrow, quad * 8), xi1 = frag(nrow, 32 + quad * 8);
        #pragma unroll
        for (int nt = 0; nt < 4; ++nt) {
            baseD[nt] = __builtin_amdgcn_mfma_f32_16x16x32_bf16(xi0, bd[nt][0], baseD[nt], 0, 0, 0);
            baseD[nt] = __builtin_amdgcn_mfma_f32_16x16x32_bf16(xi1, bd[nt][1], baseD[nt], 0, 0, 0);
        }
    }
    int idx[16];
    #pragma unroll
    for (int n = 0; n < 16; ++n) idx[n] = src[group * 256 + n * DEG + col];
    s16x8 xa[3][2];
    #pragma unroll
    for (int p = 0; p < 2; ++p) {
        xa[p][0] = frag(idx[p], quad * 8); xa[p][1] = frag(idx[p], 32 + quad * 8);
    }
    #pragma unroll
    for (int n = 0; n < 16; ++n) {
        if (n + 2 < 16) {
            xa[(n + 2) % 3][0] = frag(idx[n + 2], quad * 8);
            xa[(n + 2) % 3][1] = frag(idx[n + 2], 32 + quad * 8);
        }
        const int slane = ((n >> 2) << 4) | col;
        f32x4 acc[4];
        #pragma unroll
        for (int nt = 0; nt < 4; ++nt) {
            float bb = __shfl(baseD[nt][n & 3], slane);
            acc[nt] = (f32x4){bb, bb, bb, bb};
        }
        #pragma unroll
        for (int nt = 0; nt < 4; ++nt) {
            acc[nt] = __builtin_amdgcn_mfma_f32_16x16x32_bf16(xa[n % 3][0], b2[nt][0], acc[nt], 0, 0, 0);
            acc[nt] = __builtin_amdgcn_mfma_f32_16x16x32_bf16(xa[n % 3][1], b2[nt][1], acc[nt], 0, 0, 0);
        }
        float m[4];
        #pragma unroll
        for (int nt = 0; nt < 4; ++nt) {
            float t = fmaxf(fmaxf(acc[nt][0], acc[nt][1]),
                            fmaxf(acc[nt][2], acc[nt][3]));
            t = fmaxf(t, __shfl_xor(t, 16));
            t = fmaxf(t, __shfl_xor(t, 32));
            m[nt] = t;
        }
        float r = quad == 0 ? m[0] : quad == 1 ? m[1] : quad == 2 ? m[2] : m[3];
        out[(group * 16 + n) * C + lane] = fmaxf(r, 0.0f);
    }
}

extern "C" void kernel_launch(void* const* d_in, const int* in_sizes, int n_in,
                              void* d_out, int out_size, void* d_ws, size_t ws_size,
                              hipStream_t stream) {
    const float* x    = (const float*)d_in[0];
    const int*   src  = (const int*)  d_in[1];   // row 0 of edge_index
    const float* W    = (const float*)d_in[3];
    const float* b    = (const float*)d_in[4];
    float*       out  = (float*)d_out;

    const int n_nodes = in_sizes[0] / C;                 // 50000
    const size_t need = ((size_t)n_nodes * C + 16 * 64 * 8) * sizeof(unsigned short);

    if (ws_size >= need) {
        unsigned short* ws_u = (unsigned short*)d_ws;
        const int n4 = n_nodes * C / 4;                  // 800000
        const int n_groups = (n_nodes + NPW - 1) / NPW;  // 6250
        const int grid = (n_groups + WPB - 1) / WPB;     // 1563
        prep<<<(n4 + 255) / 256, 256, 0, stream>>>(x, W, ws_u, n4);
        edgeconv_mfma<<<grid, 256, 0, stream>>>(ws_u, src, b, out, n_groups, n_nodes);
    } else {
        const int n_groups = (n_nodes + 15) / 16;
        edgeconv_fallback<<<(n_groups + WPB - 1) / WPB, 256, 0, stream>>>(
            x, src, W, b, out, n_groups);
    }
}